// Round 7
// baseline (396.255 us; speedup 1.0000x reference)
//
#include <hip/hip_runtime.h>
#include <hip/hip_bf16.h>

// I/O is FLOAT32 (reference dtype). bf16 only internal (MFMA operands).
typedef __bf16 bf16_t;
typedef bf16_t bf16x8 __attribute__((ext_vector_type(8)));
typedef bf16_t bf16x4 __attribute__((ext_vector_type(4)));
typedef float  f32x4  __attribute__((ext_vector_type(4)));
typedef int    i32x2  __attribute__((ext_vector_type(2)));
typedef int    i32x4  __attribute__((ext_vector_type(4)));

#define MFMA(a,b,c) __builtin_amdgcn_mfma_f32_16x16x32_bf16((a),(b),(c),0,0,0)

// device-scope spin barrier (20 co-resident blocks; ctr zeroed by memsetAsync each launch)
__device__ __forceinline__ void gbar(int* ctr, int phase, int nblk) {
  __syncthreads();
  if (threadIdx.x == 0) {
    __hip_atomic_fetch_add(&ctr[phase], 1, __ATOMIC_RELEASE, __HIP_MEMORY_SCOPE_AGENT);
    while (__hip_atomic_load(&ctr[phase], __ATOMIC_ACQUIRE, __HIP_MEMORY_SCOPE_AGENT) < nblk)
      __builtin_amdgcn_s_sleep(2);
  }
  __syncthreads();
}

// ---------------- M = final_w[:, :256] @ gw_w (bf16) ----------------
__global__ __launch_bounds__(256) void k_M(const float* final_w, const float* gw_w, bf16_t* M16) {
  int o = blockIdx.x, c = threadIdx.x;
  __shared__ float fw[256];
  fw[c] = final_w[o*512 + c];
  __syncthreads();
  float acc = 0.f;
  for (int k = 0; k < 256; ++k) acc += fw[k] * gw_w[k*256 + c];
  M16[o*256 + c] = (bf16_t)acc;
}

// ---------------- x transpose: xTg[b][c][q] = x_flat[b][q*256+c] (bf16) ----------------
__global__ __launch_bounds__(256) void k_trans(const float* x, bf16_t* xTg) {
  int b = blockIdx.y;
  int q = blockIdx.x*64 + (threadIdx.x & 63);
  int w = threadIdx.x >> 6;
  const float* xr = x + b*262144 + q*256;
  bf16_t* o = xTg + b*262144 + q;
  for (int c0 = w*64; c0 < w*64 + 64; c0 += 4) {
    f32x4 v = *(const f32x4*)(xr + c0);
    o[(c0+0)*1024] = (bf16_t)v[0];
    o[(c0+1)*1024] = (bf16_t)v[1];
    o[(c0+2)*1024] = (bf16_t)v[2];
    o[(c0+3)*1024] = (bf16_t)v[3];
  }
}

// ---------------- fused small graph chain: grid 20, block 320 ----------------
// P0 tiled over 15 blocks: block k<15 -> mat=k/5, colchunk=(k%5)*64.
__global__ __launch_bounds__(320) void k_graph(const float* emb, const float* adj,
    const float* wq, const float* bq, const float* wk, const float* bk,
    const float* wv, const float* bv, const float* wo, const float* bo,
    const float* gc1_w, const float* gc2_w, const float* final_w,
    int* bar, float* qkv, float* n1, float* n2, float* h1, float* h2,
    float* rg, float* u) {
  int j = blockIdx.x, t = threadIdx.x;
  __shared__ float er_all[20][304];
  __shared__ float wtile[100][64];
  __shared__ float ks[6000], qrow[304], n2s[304];
  __shared__ float att_s[20], drt_l[20], adjr[20], g1s[256], p2red[16];
  // stage all emb rows (shared by P0 tiles and P3)
  for (int i = t; i < 6000; i += 320) er_all[i/300][i%300] = emb[i];
  __syncthreads();
  // ---- P0: qkv = emb @ {wq,wk,wv} + bias, tiled ----
  if (j < 15) {
    int mat = j / 5, c0 = (j % 5) * 64;
    const float* Wm = mat == 0 ? wq : (mat == 1 ? wk : wv);
    const float* Bv = mat == 0 ? bq : (mat == 1 ? bk : bv);
    int r = t >> 4, ci = t & 15;          // r<20 rows, ci*4 col offset
    f32x4 acc = {0.f, 0.f, 0.f, 0.f};
    for (int d0 = 0; d0 < 300; d0 += 100) {
      __syncthreads();
      for (int i = t; i < 6400; i += 320) {
        int dd = i >> 6, cc = i & 63;
        wtile[dd][cc] = (c0 + cc < 300) ? Wm[(d0+dd)*300 + c0 + cc] : 0.f;
      }
      __syncthreads();
      #pragma unroll 4
      for (int dd = 0; dd < 100; ++dd) {
        float e = er_all[r][d0+dd];
        f32x4 wv4 = *(const f32x4*)&wtile[dd][ci*4];
        acc += e * wv4;
      }
    }
    #pragma unroll
    for (int e = 0; e < 4; ++e) {
      int c = c0 + ci*4 + e;
      if (c < 300) qkv[mat*6000 + r*300 + c] = acc[e] + Bv[c];
    }
  }
  gbar(bar, 0, 20);
  // ---- P1: att row j, n1 partial, adjn row j ----
  for (int i = t; i < 6000; i += 320) ks[i] = qkv[6000 + i];
  if (t < 300) qrow[t] = qkv[j*300 + t];
  if (t >= 300 && t < 320) {
    int i = t - 300; float s = 1.f;
    for (int jj = 0; jj < 20; ++jj) s += adj[i*20 + jj];
    drt_l[i] = rsqrtf(s);
  }
  if (t < 16) p2red[t] = 0.f;
  __syncthreads();
  if (t < 20) {
    float acc = 0.f;
    #pragma unroll 4
    for (int d = 0; d < 300; ++d) acc += qrow[d] * ks[t*300 + d];
    att_s[t] = acc * 0.05773502691896258f;
  }
  __syncthreads();
  if (t == 0) {
    float m = -1e30f;
    for (int jj = 0; jj < 20; ++jj) m = fmaxf(m, att_s[jj]);
    float s = 0.f;
    for (int jj = 0; jj < 20; ++jj) { float e = __expf(att_s[jj] - m); att_s[jj] = e; s += e; }
    float inv = 0.05f / s;              // includes mean over i (1/20)
    for (int jj = 0; jj < 20; ++jj) att_s[jj] *= inv;
  }
  __syncthreads();
  if (t < 300) {
    const float* v = qkv + 12000;
    float acc = 0.f;
    for (int jj = 0; jj < 20; ++jj) acc += att_s[jj] * v[jj*300 + t];
    atomicAdd(&n1[t], acc);
  }
  if (t < 20) {
    float a = adj[j*20 + t] + (t == j ? 1.f : 0.f);
    adjr[t] = drt_l[j] * a * drt_l[t];
  }
  gbar(bar, 1, 20);
  // ---- P2: n2 cols [j*15, j*15+15), split-d over 300 threads ----
  if (t < 300) qrow[t] = n1[t];     // reuse qrow as n1 staging
  __syncthreads();
  if (t < 300) {
    int col = t % 15, dseg = t / 15;       // dseg < 20, 15 d each
    int cg = j*15 + col;
    float part = 0.f;
    #pragma unroll
    for (int dd = 0; dd < 15; ++dd) {
      int d = dseg*15 + dd;
      part += qrow[d] * wo[d*300 + cg];
    }
    atomicAdd(&p2red[col], part);
  }
  __syncthreads();
  if (t < 15) n2[j*15 + t] = p2red[t] + bo[j*15 + t];
  gbar(bar, 2, 20);
  // ---- P3: h1 row j = (emb_j + n2) @ gc1_w ----
  for (int i = t; i < 300; i += 320) n2s[i] = n2[i];
  __syncthreads();
  if (t < 256) {
    float acc = 0.f;
    #pragma unroll 4
    for (int d = 0; d < 300; ++d) acc += (er_all[j][d] + n2s[d]) * gc1_w[d*256 + t];
    h1[j*256 + t] = acc;
  }
  gbar(bar, 3, 20);
  // ---- P4: g1 row j, h2 row j ----
  if (t < 256) {
    float acc = 0.f;
    #pragma unroll
    for (int m = 0; m < 20; ++m) acc += adjr[m] * h1[m*256 + t];
    g1s[t] = fmaxf(acc, 0.f);
  }
  __syncthreads();
  if (t < 256) {
    float acc = 0.f;
    #pragma unroll 4
    for (int d = 0; d < 256; ++d) acc += g1s[d] * gc2_w[d*256 + t];
    h2[j*256 + t] = acc;
  }
  gbar(bar, 4, 20);
  // ---- P5: g2 row j -> rg ----
  if (t < 256) {
    float acc = 0.f;
    #pragma unroll
    for (int m = 0; m < 20; ++m) acc += adjr[m] * h2[m*256 + t];
    atomicAdd(&rg[t], fmaxf(acc, 0.f));
  }
  gbar(bar, 5, 20);
  // ---- P6: u = final_w[:,256:] @ rg ----
  if (j == 0 && t < 256) {
    float acc = 0.f;
    #pragma unroll 4
    for (int k = 0; k < 256; ++k) acc += final_w[t*512 + 256 + k] * rg[k];
    u[t] = acc;
  }
}

// ---------------- big path ----------------

// phi -> fBT[b][q][32] (q-major, m>=16 zero) AND fBn[b][m][q] (phi-flat layout),
// fmax, csum + cmax, s_raw, xsum (in-loop wave reduction).  grid (8, 16).
__global__ __launch_bounds__(256) void k_phis(const float* x, const float* phi_w,
    const float* phi_b, const float* s2l_w,
    bf16_t* fBT, bf16_t* fBn, float* fmaxb, float* s_raw, float* xsum,
    float* csum, float* cmaxb) {
  int b = blockIdx.y, role = blockIdx.x, t = threadIdx.x;
  const float* xb = x + b*262144;
  __shared__ float pw[4096], wi[256], pb[16], xacc[256];
  __shared__ float phs[128][18];
  __shared__ unsigned fmu[16];
  __shared__ unsigned cmu;
  for (int i = t; i < 4096; i += 256) pw[i] = phi_w[i];
  wi[t] = s2l_w[t];
  xacc[t] = 0.f;
  if (t < 16) { pb[t] = phi_b[t]; fmu[t] = 0u; }
  if (t == 0) cmu = 0u;
  __syncthreads();
  int hwl = t & 127, half = t >> 7;
  int hw = role*128 + hwl;
  int lane = t & 63;
  float ph[16];
  #pragma unroll
  for (int o = 0; o < 16; ++o) ph[o] = 0.f;
  float sacc = 0.f;
  for (int ci = 0; ci < 128; ++ci) {
    int c = half*128 + ci;
    float xv = xb[c*1024 + hw];
    sacc += wi[c] * xv;
    #pragma unroll
    for (int o = 0; o < 16; ++o) ph[o] += pw[o*256 + c] * xv;
    // xsum partial: reduce xv over the wave's 64 hw, accumulate per-c
    float red = xv;
    #pragma unroll
    for (int off = 32; off; off >>= 1) red += __shfl_xor(red, off, 64);
    if (lane == 0) atomicAdd(&xacc[c], red);
  }
  if (half == 0) {
    #pragma unroll
    for (int o = 0; o < 16; ++o) phs[hwl][o] = ph[o];
    phs[hwl][16] = sacc;
  }
  __syncthreads();
  if (half == 1) {
    #pragma unroll
    for (int o = 0; o < 16; ++o) phs[hwl][o] += ph[o];
    s_raw[b*1024 + hw] = phs[hwl][16] + sacc;
  }
  atomicAdd(&xsum[b*256 + t], xacc[t]);
  __syncthreads();
  if (half == 0) {   // threads 0..127: finalize row hw (all 16 m)
    float cs = 0.f;
    bf16x8 v0, v1, vz;
    #pragma unroll
    for (int o = 0; o < 16; ++o) {
      float val = fmaxf(phs[hwl][o] + pb[o], 0.f);
      bf16_t bv = (bf16_t)val;
      float vf = (float)bv;
      atomicMax(&fmu[o], __float_as_uint(vf));
      cs += vf;
      if (o < 8) v0[o] = bv; else v1[o-8] = bv;
      fBn[b*16384 + o*1024 + hw] = bv;     // natural (phi-flat) layout
    }
    #pragma unroll
    for (int o = 0; o < 8; ++o) vz[o] = (bf16_t)0.f;
    bf16_t* row = fBT + (b*1024 + hw)*32;
    *(bf16x8*)(row)      = v0;
    *(bf16x8*)(row + 8)  = v1;
    *(bf16x8*)(row + 16) = vz;
    *(bf16x8*)(row + 24) = vz;
    csum[b*1024 + hw] = cs;
    atomicMax(&cmu, __float_as_uint(cs));  // cs >= 0
  }
  __syncthreads();
  if (t < 16) atomicMax((unsigned*)&fmaxb[b*16 + t], fmu[t]);
  if (t == 0) atomicMax((unsigned*)&cmaxb[b], cmu);
}

// dgd = sigmoid(g)-0.5; mcol = softmax_p(s_raw).  grid 16
__global__ __launch_bounds__(256) void k_dgm(const float* xsum, const float* glob_w,
    const float* s_raw, float* dgd, float* mcol) {
  int b = blockIdx.x, t = threadIdx.x;
  __shared__ float xm[256], red[8];
  xm[t] = xsum[b*256 + t] * (1.f / 1024.f);
  __syncthreads();
  if (t < 16) {
    float g = 0.f;
    for (int c = 0; c < 256; ++c) g += glob_w[t*256 + c] * xm[c];
    dgd[b*16 + t] = 0.5f * tanhf(0.5f * g);
  }
  float v[4]; float m = -1e30f;
  #pragma unroll
  for (int i = 0; i < 4; ++i) { v[i] = s_raw[b*1024 + t + i*256]; m = fmaxf(m, v[i]); }
  #pragma unroll
  for (int off = 32; off; off >>= 1) m = fmaxf(m, __shfl_xor(m, off, 64));
  if ((t & 63) == 0) red[t >> 6] = m;
  __syncthreads();
  float bm = fmaxf(fmaxf(red[0], red[1]), fmaxf(red[2], red[3]));
  float e[4]; float sum = 0.f;
  #pragma unroll
  for (int i = 0; i < 4; ++i) { e[i] = __expf(v[i] - bm); sum += e[i]; }
  #pragma unroll
  for (int off = 32; off; off >>= 1) sum += __shfl_xor(sum, off, 64);
  if ((t & 63) == 0) red[4 + (t >> 6)] = sum;
  __syncthreads();
  float inv = 1.f / (red[4] + red[5] + red[6] + red[7]);
  #pragma unroll
  for (int i = 0; i < 4; ++i) mcol[b*1024 + t + i*256] = e[i] * inv;
}

// Fused main. grid 256 (XCD-swizzled), block 512 (8 waves: psub = w&3, chalf = w>>2).
__global__ __launch_bounds__(512) void k_main(const float* x, const bf16_t* fBT,
    const bf16_t* fBn, const bf16_t* xTg, const bf16_t* M16, const float* fmaxb,
    const float* mcol, const float* u, const float* dgd, const float* csum,
    const float* cmaxb, float* out) {
  int id = blockIdx.x;
  int b = 2*(id & 7) + (id >> 7);        // same-b blocks -> same XCD
  int p0 = ((id >> 3) & 15) * 64;
  int t = threadIdx.x, w = t >> 6, l = t & 63, lr = l & 15, quad = l >> 4;
  int psub = w & 3, chalf = w >> 2;
  __shared__ bf16_t e_s[64*40];          // e' (m>=16 zero)
  __shared__ bf16_t T_ls[64*264];
  __shared__ float fmax_s[16], dgd_s[16], u_s[256], c_s[1024];
  __shared__ float Mb_s[64], ha_s[64], rsinv_s[64];
  const float*  xb   = x   + b*262144;
  const bf16_t* fBTb = fBT + b*32768;
  const bf16_t* fBnb = fBn + b*16384;
  const bf16_t* xTb  = xTg + b*262144;
  for (int i = t; i < 2560; i += 512) e_s[i] = (bf16_t)0.f;
  if (t < 256) u_s[t] = u[t];
  for (int i = t; i < 1024; i += 512) c_s[i] = csum[b*1024 + i];
  if (t < 16) { fmax_s[t] = fmaxb[b*16 + t]; dgd_s[t] = dgd[b*16 + t]; }
  __syncthreads();
  for (int i = t; i < 1024; i += 512) {  // e'[p,m] = x_phi[p][m]*dgd[m]; x_phi = phi-flat view
    int p = i >> 4, m = i & 15;
    e_s[p*40 + m] = (bf16_t)((float)fBnb[p0*16 + i] * dgd_s[m]);
  }
  __syncthreads();
  if (t < 64) {
    float a = 0.f;
    #pragma unroll
    for (int m = 0; m < 16; ++m) a += (float)fBnb[(p0 + t)*16 + m];
    float ha = 0.5f * a;
    ha_s[t] = ha;
    float mb = ha * cmaxb[b];
    #pragma unroll
    for (int m = 0; m < 16; ++m) mb += fmaxf((float)e_s[t*40 + m], 0.f) * fmax_s[m];
    Mb_s[t] = mb;                        // exact upper bound on row max of S
  }
  __syncthreads();
  bf16x8 be = *(const bf16x8*)(e_s + (psub*16 + lr)*40 + quad*8);
  float mb_lane = Mb_s[psub*16 + lr];
  float ha_lane = ha_s[psub*16 + lr];
  int srcA = ((quad & 1)*32 + lr) * 4;   // bpermute byte addr
  int srcB = srcA + 64;
  int sel  = quad >> 1;
  float rs = 0.f;
  f32x4 acc[8];                          // S2u[p=psub*16+quad*4+r][c=chalf*128+cf*16+lr]
  #pragma unroll
  for (int i = 0; i < 8; ++i) acc[i] = (f32x4){0.f, 0.f, 0.f, 0.f};
  for (int st = 0; st < 32; ++st) {
    const bf16_t* fr = fBTb + st*32*32;
    bf16x8 a0 = *(const bf16x8*)(fr + lr*32 + quad*8);
    bf16x8 a1 = *(const bf16x8*)(fr + (16 + lr)*32 + quad*8);
    f32x4 z = {0.f, 0.f, 0.f, 0.f};
    f32x4 s0 = MFMA(a0, be, z);          // s0[r] = S[p=psub*16+lr][q=st*32+quad*4+r]
    f32x4 s1 = MFMA(a1, be, z);          // s1: q = st*32+16+quad*4+r
    bf16x4 e0, e1;
    #pragma unroll
    for (int r = 0; r < 4; ++r) {
      float S0 = s0[r] + ha_lane * c_s[st*32 + quad*4 + r];
      float S1 = s1[r] + ha_lane * c_s[st*32 + 16 + quad*4 + r];
      float E0 = __expf(S0 - mb_lane);
      float E1 = __expf(S1 - mb_lane);
      rs += E0 + E1;
      e0[r] = (bf16_t)E0; e1[r] = (bf16_t)E1;
    }
    // in-wave D-layout -> A-layout transpose of E via bpermute
    i32x2 pe0 = __builtin_bit_cast(i32x2, e0);
    i32x2 pe1 = __builtin_bit_cast(i32x2, e1);
    int t00 = __builtin_amdgcn_ds_bpermute(srcA, pe0[0]);
    int t01 = __builtin_amdgcn_ds_bpermute(srcA, pe0[1]);
    int t02 = __builtin_amdgcn_ds_bpermute(srcB, pe0[0]);
    int t03 = __builtin_amdgcn_ds_bpermute(srcB, pe0[1]);
    int t10 = __builtin_amdgcn_ds_bpermute(srcA, pe1[0]);
    int t11 = __builtin_amdgcn_ds_bpermute(srcA, pe1[1]);
    int t12 = __builtin_amdgcn_ds_bpermute(srcB, pe1[0]);
    int t13 = __builtin_amdgcn_ds_bpermute(srcB, pe1[1]);
    i32x4 av = { sel ? t10 : t00, sel ? t11 : t01, sel ? t12 : t02, sel ? t13 : t03 };
    bf16x8 af = __builtin_bit_cast(bf16x8, av);   // af[j] = E[p=psub*16+lr][q=quad*8+j]
    #pragma unroll
    for (int cf = 0; cf < 8; ++cf) {
      bf16x8 bv = *(const bf16x8*)(xTb + (chalf*128 + cf*16 + lr)*1024 + st*32 + quad*8);
      acc[cf] = MFMA(af, bv, acc[cf]);
    }
  }
  rs += __shfl_xor(rs, 16, 64);
  rs += __shfl_xor(rs, 32, 64);          // full rowsum for p = psub*16+lr
  float inv_l = 1.f / fmaxf(rs, 1e-30f);
  if (w < 4 && l < 16) rsinv_s[psub*16 + lr] = inv_l;
  __syncthreads();
  #pragma unroll
  for (int cf = 0; cf < 8; ++cf)
    #pragma unroll
    for (int r = 0; r < 4; ++r) {
      int p = psub*16 + quad*4 + r;
      int c = chalf*128 + cf*16 + lr;
      float tv = xb[(p0 + p)*256 + c] - acc[cf][r] * rsinv_s[p];
      T_ls[p*264 + c] = (bf16_t)tv;      // spiral[p][c]
    }
  __syncthreads();
  f32x4 acc2[2][4];                      // D2[o=w*32+of*16+quad*4+r][p=pf*16+lr]
  #pragma unroll
  for (int i = 0; i < 2; ++i)
    #pragma unroll
    for (int j = 0; j < 4; ++j) acc2[i][j] = (f32x4){0.f, 0.f, 0.f, 0.f};
  for (int c0 = 0; c0 < 256; c0 += 32) {
    bf16x8 am[2], bt[4];
    #pragma unroll
    for (int of = 0; of < 2; ++of)
      am[of] = *(const bf16x8*)(M16 + (w*32 + of*16 + lr)*256 + c0 + quad*8);
    #pragma unroll
    for (int pf = 0; pf < 4; ++pf)
      bt[pf] = *(const bf16x8*)(T_ls + (pf*16 + lr)*264 + c0 + quad*8);
    #pragma unroll
    for (int of = 0; of < 2; ++of)
      #pragma unroll
      for (int pf = 0; pf < 4; ++pf) acc2[of][pf] = MFMA(am[of], bt[pf], acc2[of][pf]);
  }
  float* outb = out + b*262144;
  #pragma unroll
  for (int of = 0; of < 2; ++of)
    #pragma unroll
    for (int pf = 0; pf < 4; ++pf)
      #pragma unroll
      for (int r = 0; r < 4; ++r) {
        int o = w*32 + of*16 + quad*4 + r;
        int pg = p0 + pf*16 + lr;
        float v = acc2[of][pf][r] + mcol[b*1024 + pg] * u_s[o] + xb[o*1024 + pg];
        outb[o*1024 + pg] = fmaxf(v, 0.f);
      }
}

// ---------------- launch ----------------

extern "C" void kernel_launch(void* const* d_in, const int* in_sizes, int n_in,
                              void* d_out, int out_size, void* d_ws, size_t ws_size,
                              hipStream_t stream) {
  (void)in_sizes; (void)n_in; (void)out_size; (void)ws_size;
  const float* x       = (const float*)d_in[0];
  const float* emb     = (const float*)d_in[1];
  const float* adj     = (const float*)d_in[2];
  const float* wq      = (const float*)d_in[3];
  const float* bq      = (const float*)d_in[4];
  const float* wk      = (const float*)d_in[5];
  const float* bk      = (const float*)d_in[6];
  const float* wv      = (const float*)d_in[7];
  const float* bv      = (const float*)d_in[8];
  const float* wo      = (const float*)d_in[9];
  const float* bo      = (const float*)d_in[10];
  const float* phi_w   = (const float*)d_in[11];
  const float* phi_b   = (const float*)d_in[12];
  const float* glob_w  = (const float*)d_in[13];
  const float* gc1_w   = (const float*)d_in[14];
  const float* gc2_w   = (const float*)d_in[15];
  const float* gw_w    = (const float*)d_in[16];
  const float* s2l_w   = (const float*)d_in[17];
  const float* final_w = (const float*)d_in[19];
  float* out = (float*)d_out;

  float* W = (float*)d_ws;
  // zero region [0, 4960 floats): bar | rg | n1 | xsum | fmaxb | cmaxb
  int*   bar   = (int*)W;          // 32 ints
  float* rg    = W + 32;           // 256
  float* n1    = W + 288;          // 304
  float* xsum  = W + 592;          // 4096
  float* fmaxb = W + 4688;         // 256
  float* cmaxb = W + 4944;         // 16
  float* qkv   = W + 4960;         // 18000
  float* n2    = W + 22960;        // 304
  float* h1    = W + 23264;        // 5120
  float* h2    = W + 28384;        // 5120
  float* u     = W + 33504;        // 256
  float* s_raw = W + 33760;        // 16384
  float* mcol  = W + 50144;        // 16384
  float* csum  = W + 66528;        // 16384
  float* dgd   = W + 82912;        // 256
  bf16_t* M16 = (bf16_t*)((char*)d_ws + 335872);   // 128 KB
  bf16_t* fBT = (bf16_t*)((char*)d_ws + 466944);   // 1 MB   (16 x 1024 x 32)
  bf16_t* fBn = (bf16_t*)((char*)d_ws + 1515520);  // 512 KB (16 x 16 x 1024, phi-flat)
  bf16_t* xTg = (bf16_t*)((char*)d_ws + 2039808);  // 8 MB   (16 x 256 x 1024)
  // total ws usage ~10.0 MB

  hipMemsetAsync(d_ws, 0, 4960 * sizeof(float), stream);
  k_phis <<<dim3(8, 16), 256, 0, stream>>>(x, phi_w, phi_b, s2l_w, fBT, fBn, fmaxb, s_raw, xsum, csum, cmaxb);
  k_trans<<<dim3(16, 16), 256, 0, stream>>>(x, xTg);
  k_M    <<<256, 256, 0, stream>>>(final_w, gw_w, M16);
  k_graph<<<20, 320, 0, stream>>>(emb, adj, wq, bq, wk, bk, wv, bv, wo, bo,
                                  gc1_w, gc2_w, final_w, bar, qkv, n1, n2, h1, h2, rg, u);
  k_dgm  <<<16, 256, 0, stream>>>(xsum, glob_w, s_raw, dgd, mcol);
  k_main <<<256, 512, 0, stream>>>(x, fBT, fBn, xTg, M16, fmaxb, mcol, u, dgd, csum, cmaxb, out);
}

// Round 8
// 357.320 us; speedup vs baseline: 1.1090x; 1.1090x over previous
//
#include <hip/hip_runtime.h>
#include <hip/hip_bf16.h>

// I/O is FLOAT32 (reference dtype). bf16 only internal (MFMA operands).
typedef __bf16 bf16_t;
typedef bf16_t bf16x8 __attribute__((ext_vector_type(8)));
typedef bf16_t bf16x4 __attribute__((ext_vector_type(4)));
typedef float  f32x4  __attribute__((ext_vector_type(4)));
typedef int    i32x2  __attribute__((ext_vector_type(2)));
typedef int    i32x4  __attribute__((ext_vector_type(4)));

#define MFMA(a,b,c) __builtin_amdgcn_mfma_f32_16x16x32_bf16((a),(b),(c),0,0,0)

// relaxed device-scope data exchange (bypass local caches, no bulk flush)
__device__ __forceinline__ float gld(const float* p) {
  return __hip_atomic_load(p, __ATOMIC_RELAXED, __HIP_MEMORY_SCOPE_AGENT);
}
__device__ __forceinline__ void gst(float* p, float v) {
  __hip_atomic_store(p, v, __ATOMIC_RELAXED, __HIP_MEMORY_SCOPE_AGENT);
}

// relaxed spin barrier: __syncthreads() drains each wave's vmcnt before the bump,
// so all block stores (sc-coherent) are at the coherence point before release.
__device__ __forceinline__ void gbar(int* ctr, int phase, int nblk) {
  __syncthreads();
  if (threadIdx.x == 0) {
    __hip_atomic_fetch_add(&ctr[phase], 1, __ATOMIC_RELAXED, __HIP_MEMORY_SCOPE_AGENT);
    while (__hip_atomic_load(&ctr[phase], __ATOMIC_RELAXED, __HIP_MEMORY_SCOPE_AGENT) < nblk)
      __builtin_amdgcn_s_sleep(8);
  }
  __syncthreads();
}

// ---------------- M = final_w[:, :256] @ gw_w (bf16) ----------------
__global__ __launch_bounds__(256) void k_M(const float* final_w, const float* gw_w, bf16_t* M16) {
  int o = blockIdx.x, c = threadIdx.x;
  __shared__ float fw[256];
  fw[c] = final_w[o*512 + c];
  __syncthreads();
  float acc = 0.f;
  for (int k = 0; k < 256; ++k) acc += fw[k] * gw_w[k*256 + c];
  M16[o*256 + c] = (bf16_t)acc;
}

// ---------------- x transpose: xTg[b][c][q] = x_flat[b][q*256+c] (bf16) ----------------
__global__ __launch_bounds__(256) void k_trans(const float* x, bf16_t* xTg) {
  int b = blockIdx.y;
  int q = blockIdx.x*64 + (threadIdx.x & 63);
  int w = threadIdx.x >> 6;
  const float* xr = x + b*262144 + q*256;
  bf16_t* o = xTg + b*262144 + q;
  for (int c0 = w*64; c0 < w*64 + 64; c0 += 4) {
    f32x4 v = *(const f32x4*)(xr + c0);
    o[(c0+0)*1024] = (bf16_t)v[0];
    o[(c0+1)*1024] = (bf16_t)v[1];
    o[(c0+2)*1024] = (bf16_t)v[2];
    o[(c0+3)*1024] = (bf16_t)v[3];
  }
}

// ---------------- xsum[b][c] = sum_hw x[b][c][hw]   grid (16,16) ----------------
__global__ __launch_bounds__(256) void k_xsum(const float* x, float* xsum) {
  int b = blockIdx.y, cx = blockIdx.x;
  int t = threadIdx.x, w = t >> 6, lane = t & 63;
  const float* xb = x + b*262144;
  #pragma unroll
  for (int rr = 0; rr < 4; ++rr) {
    int c = cx*16 + w*4 + rr;
    const f32x4* p = (const f32x4*)(xb + c*1024);
    float s = 0.f;
    #pragma unroll
    for (int k = 0; k < 4; ++k) {
      f32x4 v = p[k*64 + lane];
      s += v[0] + v[1] + v[2] + v[3];
    }
    #pragma unroll
    for (int off = 32; off; off >>= 1) s += __shfl_xor(s, off, 64);
    if (lane == 0) xsum[b*256 + c] = s;
  }
}

// ---------------- fused small graph chain: grid 20, block 320 ----------------
__global__ __launch_bounds__(320) void k_graph(const float* emb, const float* adj,
    const float* wq, const float* bq, const float* wk, const float* bk,
    const float* wv, const float* bv, const float* wo, const float* bo,
    const float* gc1_w, const float* gc2_w, const float* final_w,
    int* bar, float* qkv, float* n1, float* n2, float* h1, float* h2,
    float* rg, float* u) {
  int j = blockIdx.x, t = threadIdx.x;
  __shared__ float er[304], n2s[304], ks[6000], qrow[304];
  __shared__ float att_s[20], drt_l[20], adjr[20], g1s[256], p2red[16];
  // P0: q,k,v rows for node j
  if (t < 300) er[t] = emb[j*300 + t];
  __syncthreads();
  if (t < 300) {
    float aq = bq[t], ak = bk[t], av = bv[t];
    for (int d = 0; d < 300; ++d) {
      float e = er[d];
      aq += e * wq[d*300 + t];
      ak += e * wk[d*300 + t];
      av += e * wv[d*300 + t];
    }
    gst(&qkv[j*300 + t], aq);
    gst(&qkv[6000 + j*300 + t], ak);
    gst(&qkv[12000 + j*300 + t], av);
  }
  gbar(bar, 0, 20);
  // P1: att row j, n1 partial, adjn row j
  for (int i = t; i < 6000; i += 320) ks[i] = gld(&qkv[6000 + i]);
  if (t < 300) qrow[t] = gld(&qkv[j*300 + t]);
  if (t >= 300 && t < 320) {
    int i = t - 300; float s = 1.f;
    for (int jj = 0; jj < 20; ++jj) s += adj[i*20 + jj];
    drt_l[i] = rsqrtf(s);
  }
  if (t < 16) p2red[t] = 0.f;
  __syncthreads();
  if (t < 20) {
    float acc = 0.f;
    #pragma unroll 4
    for (int d = 0; d < 300; ++d) acc += qrow[d] * ks[t*300 + d];
    att_s[t] = acc * 0.05773502691896258f;
  }
  __syncthreads();
  if (t == 0) {
    float m = -1e30f;
    for (int jj = 0; jj < 20; ++jj) m = fmaxf(m, att_s[jj]);
    float s = 0.f;
    for (int jj = 0; jj < 20; ++jj) { float e = __expf(att_s[jj] - m); att_s[jj] = e; s += e; }
    float inv = 0.05f / s;              // includes mean over i (1/20)
    for (int jj = 0; jj < 20; ++jj) att_s[jj] *= inv;
  }
  __syncthreads();
  if (t < 300) {
    float acc = 0.f;
    for (int jj = 0; jj < 20; ++jj) acc += att_s[jj] * gld(&qkv[12000 + jj*300 + t]);
    atomicAdd(&n1[t], acc);
  }
  if (t < 20) {
    float a = adj[j*20 + t] + (t == j ? 1.f : 0.f);
    adjr[t] = drt_l[j] * a * drt_l[t];
  }
  gbar(bar, 1, 20);
  // P2: n2 cols [j*15, j*15+15), split-d over 300 threads
  if (t < 300) qrow[t] = gld(&n1[t]);
  __syncthreads();
  if (t < 300) {
    int col = t % 15, dseg = t / 15;
    int cg = j*15 + col;
    float part = 0.f;
    #pragma unroll
    for (int dd = 0; dd < 15; ++dd) {
      int d = dseg*15 + dd;
      part += qrow[d] * wo[d*300 + cg];
    }
    atomicAdd(&p2red[col], part);
  }
  __syncthreads();
  if (t < 15) gst(&n2[j*15 + t], p2red[t] + bo[j*15 + t]);
  gbar(bar, 2, 20);
  // P3: h1 row j = (emb_j + n2) @ gc1_w
  for (int i = t; i < 300; i += 320) n2s[i] = gld(&n2[i]);
  __syncthreads();
  if (t < 256) {
    float acc = 0.f;
    #pragma unroll 4
    for (int d = 0; d < 300; ++d) acc += (er[d] + n2s[d]) * gc1_w[d*256 + t];
    gst(&h1[j*256 + t], acc);
  }
  gbar(bar, 3, 20);
  // P4: g1 row j, h2 row j
  if (t < 256) {
    float acc = 0.f;
    #pragma unroll
    for (int m = 0; m < 20; ++m) acc += adjr[m] * gld(&h1[m*256 + t]);
    g1s[t] = fmaxf(acc, 0.f);
  }
  __syncthreads();
  if (t < 256) {
    float acc = 0.f;
    #pragma unroll 4
    for (int d = 0; d < 256; ++d) acc += g1s[d] * gc2_w[d*256 + t];
    gst(&h2[j*256 + t], acc);
  }
  gbar(bar, 4, 20);
  // P5: g2 row j -> rg
  if (t < 256) {
    float acc = 0.f;
    #pragma unroll
    for (int m = 0; m < 20; ++m) acc += adjr[m] * gld(&h2[m*256 + t]);
    atomicAdd(&rg[t], fmaxf(acc, 0.f));
  }
  gbar(bar, 5, 20);
  // P6: u = final_w[:,256:] @ rg  (block 0; u crosses kernel boundary -> plain store ok)
  if (j == 0 && t < 256) {
    float acc = 0.f;
    #pragma unroll 4
    for (int k = 0; k < 256; ++k) acc += final_w[t*512 + 256 + k] * gld(&rg[k]);
    u[t] = acc;
  }
}

// ---------------- big path ----------------

// phi -> fBT[b][q][32] (q-major, m>=16 zero) AND fBn[b][m][q] (phi-flat layout),
// fmax, csum + cmax, s_raw.  grid (16, 16): 64 hw per block, 4-way c-split.
__global__ __launch_bounds__(256) void k_phis(const float* x, const float* phi_w,
    const float* phi_b, const float* s2l_w,
    bf16_t* fBT, bf16_t* fBn, float* fmaxb, float* s_raw,
    float* csum, float* cmaxb) {
  int b = blockIdx.y, role = blockIdx.x, t = threadIdx.x;
  const float* xb = x + b*262144;
  __shared__ float pw[4096], wi[256], pb[16];
  __shared__ float phs[4][64][21];
  __shared__ unsigned fmu[16];
  __shared__ unsigned cmu;
  for (int i = t; i < 4096; i += 256) pw[i] = phi_w[i];
  wi[t] = s2l_w[t];
  if (t < 16) { pb[t] = phi_b[t]; fmu[t] = 0u; }
  if (t == 0) cmu = 0u;
  __syncthreads();
  int hwl = t & 63, cq = t >> 6;
  int hw = role*64 + hwl;
  float ph[16];
  #pragma unroll
  for (int o = 0; o < 16; ++o) ph[o] = 0.f;
  float sacc = 0.f;
  for (int ci = 0; ci < 64; ++ci) {
    int c = cq*64 + ci;
    float xv = xb[c*1024 + hw];
    sacc += wi[c] * xv;
    #pragma unroll
    for (int o = 0; o < 16; ++o) ph[o] += pw[o*256 + c] * xv;
  }
  #pragma unroll
  for (int o = 0; o < 16; ++o) phs[cq][hwl][o] = ph[o];
  phs[cq][hwl][16] = sacc;
  __syncthreads();
  for (int idx = t; idx < 64*20; idx += 256) {
    int hh = idx / 20, o = idx % 20;
    if (o < 17)
      phs[0][hh][o] += phs[1][hh][o] + phs[2][hh][o] + phs[3][hh][o];
  }
  __syncthreads();
  if (t < 64) {
    s_raw[b*1024 + hw] = phs[0][hwl][16];
    float cs = 0.f;
    bf16x8 v0, v1, vz;
    #pragma unroll
    for (int o = 0; o < 16; ++o) {
      float val = fmaxf(phs[0][hwl][o] + pb[o], 0.f);
      bf16_t bv = (bf16_t)val;
      float vf = (float)bv;
      atomicMax(&fmu[o], __float_as_uint(vf));
      cs += vf;
      if (o < 8) v0[o] = bv; else v1[o-8] = bv;
      fBn[b*16384 + o*1024 + hw] = bv;     // natural (phi-flat) layout
    }
    #pragma unroll
    for (int o = 0; o < 8; ++o) vz[o] = (bf16_t)0.f;
    bf16_t* row = fBT + (b*1024 + hw)*32;
    *(bf16x8*)(row)      = v0;
    *(bf16x8*)(row + 8)  = v1;
    *(bf16x8*)(row + 16) = vz;
    *(bf16x8*)(row + 24) = vz;
    csum[b*1024 + hw] = cs;
    atomicMax(&cmu, __float_as_uint(cs));  // cs >= 0
  }
  __syncthreads();
  if (t < 16) atomicMax((unsigned*)&fmaxb[b*16 + t], fmu[t]);
  if (t == 0) atomicMax((unsigned*)&cmaxb[b], cmu);
}

// dgd = sigmoid(g)-0.5; mcol = softmax_p(s_raw).  grid 16
__global__ __launch_bounds__(256) void k_dgm(const float* xsum, const float* glob_w,
    const float* s_raw, float* dgd, float* mcol) {
  int b = blockIdx.x, t = threadIdx.x;
  __shared__ float xm[256], red[8];
  xm[t] = xsum[b*256 + t] * (1.f / 1024.f);
  __syncthreads();
  if (t < 16) {
    float g = 0.f;
    for (int c = 0; c < 256; ++c) g += glob_w[t*256 + c] * xm[c];
    dgd[b*16 + t] = 0.5f * tanhf(0.5f * g);
  }
  float v[4]; float m = -1e30f;
  #pragma unroll
  for (int i = 0; i < 4; ++i) { v[i] = s_raw[b*1024 + t + i*256]; m = fmaxf(m, v[i]); }
  #pragma unroll
  for (int off = 32; off; off >>= 1) m = fmaxf(m, __shfl_xor(m, off, 64));
  if ((t & 63) == 0) red[t >> 6] = m;
  __syncthreads();
  float bm = fmaxf(fmaxf(red[0], red[1]), fmaxf(red[2], red[3]));
  float e[4]; float sum = 0.f;
  #pragma unroll
  for (int i = 0; i < 4; ++i) { e[i] = __expf(v[i] - bm); sum += e[i]; }
  #pragma unroll
  for (int off = 32; off; off >>= 1) sum += __shfl_xor(sum, off, 64);
  if ((t & 63) == 0) red[4 + (t >> 6)] = sum;
  __syncthreads();
  float inv = 1.f / (red[4] + red[5] + red[6] + red[7]);
  #pragma unroll
  for (int i = 0; i < 4; ++i) mcol[b*1024 + t + i*256] = e[i] * inv;
}

// Fused main. grid 256 (XCD-swizzled), block 512 (8 waves: psub = w&3, chalf = w>>2).
__global__ __launch_bounds__(512) void k_main(const float* x, const bf16_t* fBT,
    const bf16_t* fBn, const bf16_t* xTg, const bf16_t* M16, const float* fmaxb,
    const float* mcol, const float* u, const float* dgd, const float* csum,
    const float* cmaxb, float* out) {
  int id = blockIdx.x;
  int b = 2*(id & 7) + (id >> 7);        // same-b blocks -> same XCD
  int p0 = ((id >> 3) & 15) * 64;
  int t = threadIdx.x, w = t >> 6, l = t & 63, lr = l & 15, quad = l >> 4;
  int psub = w & 3, chalf = w >> 2;
  __shared__ bf16_t e_s[64*40];          // e' (m>=16 zero)
  __shared__ bf16_t T_ls[64*264];
  __shared__ float fmax_s[16], dgd_s[16], u_s[256], c_s[1024];
  __shared__ float Mb_s[64], ha_s[64], rsinv_s[64];
  const float*  xb   = x   + b*262144;
  const bf16_t* fBTb = fBT + b*32768;
  const bf16_t* fBnb = fBn + b*16384;
  const bf16_t* xTb  = xTg + b*262144;
  for (int i = t; i < 2560; i += 512) e_s[i] = (bf16_t)0.f;
  if (t < 256) u_s[t] = u[t];
  for (int i = t; i < 1024; i += 512) c_s[i] = csum[b*1024 + i];
  if (t < 16) { fmax_s[t] = fmaxb[b*16 + t]; dgd_s[t] = dgd[b*16 + t]; }
  __syncthreads();
  for (int i = t; i < 1024; i += 512) {  // e'[p,m] = x_phi[p][m]*dgd[m]; x_phi = phi-flat view
    int p = i >> 4, m = i & 15;
    e_s[p*40 + m] = (bf16_t)((float)fBnb[p0*16 + i] * dgd_s[m]);
  }
  __syncthreads();
  if (t < 64) {
    float a = 0.f;
    #pragma unroll
    for (int m = 0; m < 16; ++m) a += (float)fBnb[(p0 + t)*16 + m];
    float ha = 0.5f * a;
    ha_s[t] = ha;
    float mb = ha * cmaxb[b];
    #pragma unroll
    for (int m = 0; m < 16; ++m) mb += fmaxf((float)e_s[t*40 + m], 0.f) * fmax_s[m];
    Mb_s[t] = mb;                        // exact upper bound on row max of S
  }
  __syncthreads();
  bf16x8 be = *(const bf16x8*)(e_s + (psub*16 + lr)*40 + quad*8);
  float mb_lane = Mb_s[psub*16 + lr];
  float ha_lane = ha_s[psub*16 + lr];
  int srcA = ((quad & 1)*32 + lr) * 4;   // bpermute byte addr
  int srcB = srcA + 64;
  int sel  = quad >> 1;
  float rs = 0.f;
  f32x4 acc[8];                          // S2u[p=psub*16+quad*4+r][c=chalf*128+cf*16+lr]
  #pragma unroll
  for (int i = 0; i < 8; ++i) acc[i] = (f32x4){0.f, 0.f, 0.f, 0.f};
  for (int st = 0; st < 32; ++st) {
    const bf16_t* fr = fBTb + st*32*32;
    bf16x8 a0 = *(const bf16x8*)(fr + lr*32 + quad*8);
    bf16x8 a1 = *(const bf16x8*)(fr + (16 + lr)*32 + quad*8);
    f32x4 z = {0.f, 0.f, 0.f, 0.f};
    f32x4 s0 = MFMA(a0, be, z);          // s0[r] = S[p=psub*16+lr][q=st*32+quad*4+r]
    f32x4 s1 = MFMA(a1, be, z);          // s1: q = st*32+16+quad*4+r
    bf16x4 e0, e1;
    #pragma unroll
    for (int r = 0; r < 4; ++r) {
      float S0 = s0[r] + ha_lane * c_s[st*32 + quad*4 + r];
      float S1 = s1[r] + ha_lane * c_s[st*32 + 16 + quad*4 + r];
      float E0 = __expf(S0 - mb_lane);
      float E1 = __expf(S1 - mb_lane);
      rs += E0 + E1;
      e0[r] = (bf16_t)E0; e1[r] = (bf16_t)E1;
    }
    // in-wave D-layout -> A-layout transpose of E via bpermute
    i32x2 pe0 = __builtin_bit_cast(i32x2, e0);
    i32x2 pe1 = __builtin_bit_cast(i32x2, e1);
    int t00 = __builtin_amdgcn_ds_bpermute(srcA, pe0[0]);
    int t01 = __builtin_amdgcn_ds_bpermute(srcA, pe0[1]);
    int t02 = __builtin_amdgcn_ds_bpermute(srcB, pe0[0]);
    int t03 = __builtin_amdgcn_ds_bpermute(srcB, pe0[1]);
    int t10 = __builtin_amdgcn_ds_bpermute(srcA, pe1[0]);
    int t11 = __builtin_amdgcn_ds_bpermute(srcA, pe1[1]);
    int t12 = __builtin_amdgcn_ds_bpermute(srcB, pe1[0]);
    int t13 = __builtin_amdgcn_ds_bpermute(srcB, pe1[1]);
    i32x4 av = { sel ? t10 : t00, sel ? t11 : t01, sel ? t12 : t02, sel ? t13 : t03 };
    bf16x8 af = __builtin_bit_cast(bf16x8, av);   // af[j] = E[p=psub*16+lr][q=quad*8+j]
    #pragma unroll
    for (int cf = 0; cf < 8; ++cf) {
      bf16x8 bv = *(const bf16x8*)(xTb + (chalf*128 + cf*16 + lr)*1024 + st*32 + quad*8);
      acc[cf] = MFMA(af, bv, acc[cf]);
    }
  }
  rs += __shfl_xor(rs, 16, 64);
  rs += __shfl_xor(rs, 32, 64);          // full rowsum for p = psub*16+lr
  float inv_l = 1.f / fmaxf(rs, 1e-30f);
  if (w < 4 && l < 16) rsinv_s[psub*16 + lr] = inv_l;
  __syncthreads();
  #pragma unroll
  for (int cf = 0; cf < 8; ++cf)
    #pragma unroll
    for (int r = 0; r < 4; ++r) {
      int p = psub*16 + quad*4 + r;
      int c = chalf*128 + cf*16 + lr;
      float tv = xb[(p0 + p)*256 + c] - acc[cf][r] * rsinv_s[p];
      T_ls[p*264 + c] = (bf16_t)tv;      // spiral[p][c]
    }
  __syncthreads();
  f32x4 acc2[2][4];                      // D2[o=w*32+of*16+quad*4+r][p=pf*16+lr]
  #pragma unroll
  for (int i = 0; i < 2; ++i)
    #pragma unroll
    for (int j = 0; j < 4; ++j) acc2[i][j] = (f32x4){0.f, 0.f, 0.f, 0.f};
  for (int c0 = 0; c0 < 256; c0 += 32) {
    bf16x8 am[2], bt[4];
    #pragma unroll
    for (int of = 0; of < 2; ++of)
      am[of] = *(const bf16x8*)(M16 + (w*32 + of*16 + lr)*256 + c0 + quad*8);
    #pragma unroll
    for (int pf = 0; pf < 4; ++pf)
      bt[pf] = *(const bf16x8*)(T_ls + (pf*16 + lr)*264 + c0 + quad*8);
    #pragma unroll
    for (int of = 0; of < 2; ++of)
      #pragma unroll
      for (int pf = 0; pf < 4; ++pf) acc2[of][pf] = MFMA(am[of], bt[pf], acc2[of][pf]);
  }
  float* outb = out + b*262144;
  #pragma unroll
  for (int of = 0; of < 2; ++of)
    #pragma unroll
    for (int pf = 0; pf < 4; ++pf)
      #pragma unroll
      for (int r = 0; r < 4; ++r) {
        int o = w*32 + of*16 + quad*4 + r;
        int pg = p0 + pf*16 + lr;
        float v = acc2[of][pf][r] + mcol[b*1024 + pg] * u_s[o] + xb[o*1024 + pg];
        outb[o*1024 + pg] = fmaxf(v, 0.f);
      }
}

// ---------------- launch ----------------

extern "C" void kernel_launch(void* const* d_in, const int* in_sizes, int n_in,
                              void* d_out, int out_size, void* d_ws, size_t ws_size,
                              hipStream_t stream) {
  (void)in_sizes; (void)n_in; (void)out_size; (void)ws_size;
  const float* x       = (const float*)d_in[0];
  const float* emb     = (const float*)d_in[1];
  const float* adj     = (const float*)d_in[2];
  const float* wq      = (const float*)d_in[3];
  const float* bq      = (const float*)d_in[4];
  const float* wk      = (const float*)d_in[5];
  const float* bk      = (const float*)d_in[6];
  const float* wv      = (const float*)d_in[7];
  const float* bv      = (const float*)d_in[8];
  const float* wo      = (const float*)d_in[9];
  const float* bo      = (const float*)d_in[10];
  const float* phi_w   = (const float*)d_in[11];
  const float* phi_b   = (const float*)d_in[12];
  const float* glob_w  = (const float*)d_in[13];
  const float* gc1_w   = (const float*)d_in[14];
  const float* gc2_w   = (const float*)d_in[15];
  const float* gw_w    = (const float*)d_in[16];
  const float* s2l_w   = (const float*)d_in[17];
  const float* final_w = (const float*)d_in[19];
  float* out = (float*)d_out;

  float* W = (float*)d_ws;
  // zero region [0, 4960 floats): bar | rg | n1 | xsum | fmaxb | cmaxb
  int*   bar   = (int*)W;          // 32 ints
  float* rg    = W + 32;           // 256
  float* n1    = W + 288;          // 304
  float* xsum  = W + 592;          // 4096
  float* fmaxb = W + 4688;         // 256
  float* cmaxb = W + 4944;         // 16
  float* qkv   = W + 4960;         // 18000
  float* n2    = W + 22960;        // 304
  float* h1    = W + 23264;        // 5120
  float* h2    = W + 28384;        // 5120
  float* u     = W + 33504;        // 256
  float* s_raw = W + 33760;        // 16384
  float* mcol  = W + 50144;        // 16384
  float* csum  = W + 66528;        // 16384
  float* dgd   = W + 82912;        // 256
  bf16_t* M16 = (bf16_t*)((char*)d_ws + 335872);   // 128 KB
  bf16_t* fBT = (bf16_t*)((char*)d_ws + 466944);   // 1 MB   (16 x 1024 x 32)
  bf16_t* fBn = (bf16_t*)((char*)d_ws + 1515520);  // 512 KB (16 x 16 x 1024, phi-flat)
  bf16_t* xTg = (bf16_t*)((char*)d_ws + 2039808);  // 8 MB   (16 x 256 x 1024)
  // total ws usage ~10.0 MB

  hipMemsetAsync(d_ws, 0, 4960 * sizeof(float), stream);
  k_phis <<<dim3(16, 16), 256, 0, stream>>>(x, phi_w, phi_b, s2l_w, fBT, fBn, fmaxb, s_raw, csum, cmaxb);
  k_xsum <<<dim3(16, 16), 256, 0, stream>>>(x, xsum);
  k_trans<<<dim3(16, 16), 256, 0, stream>>>(x, xTg);
  k_M    <<<256, 256, 0, stream>>>(final_w, gw_w, M16);
  k_graph<<<20, 320, 0, stream>>>(emb, adj, wq, bq, wk, bk, wv, bv, wo, bo,
                                  gc1_w, gc2_w, final_w, bar, qkv, n1, n2, h1, h2, rg, u);
  k_dgm  <<<16, 256, 0, stream>>>(xsum, glob_w, s_raw, dgd, mcol);
  k_main <<<256, 512, 0, stream>>>(x, fBT, fBn, xTg, M16, fmaxb, mcol, u, dgd, csum, cmaxb, out);
}

// Round 9
// 296.900 us; speedup vs baseline: 1.3346x; 1.2035x over previous
//
#include <hip/hip_runtime.h>
#include <hip/hip_bf16.h>

// I/O is FLOAT32 (reference dtype). bf16 only internal (MFMA operands).
typedef __bf16 bf16_t;
typedef bf16_t bf16x8 __attribute__((ext_vector_type(8)));
typedef bf16_t bf16x4 __attribute__((ext_vector_type(4)));
typedef float  f32x4  __attribute__((ext_vector_type(4)));

#define MFMA(a,b,c) __builtin_amdgcn_mfma_f32_16x16x32_bf16((a),(b),(c),0,0,0)

// relaxed device-scope data exchange (bypass non-coherent L1/L2, no bulk flush)
__device__ __forceinline__ float gld(const float* p) {
  return __hip_atomic_load(p, __ATOMIC_RELAXED, __HIP_MEMORY_SCOPE_AGENT);
}
__device__ __forceinline__ void gst(float* p, float v) {
  __hip_atomic_store(p, v, __ATOMIC_RELAXED, __HIP_MEMORY_SCOPE_AGENT);
}

// spin barrier among 20 co-resident blocks (ctr zeroed by memsetAsync each launch)
__device__ __forceinline__ void gbar(int* ctr, int phase, int nblk) {
  __syncthreads();
  if (threadIdx.x == 0) {
    __hip_atomic_fetch_add(&ctr[phase], 1, __ATOMIC_RELAXED, __HIP_MEMORY_SCOPE_AGENT);
    while (__hip_atomic_load(&ctr[phase], __ATOMIC_RELAXED, __HIP_MEMORY_SCOPE_AGENT) < nblk)
      __builtin_amdgcn_s_sleep(2);
  }
  __syncthreads();
}

// ---------------- M = final_w[:, :256] @ gw_w (bf16) ----------------
__global__ __launch_bounds__(256) void k_M(const float* final_w, const float* gw_w, bf16_t* M16) {
  int o = blockIdx.x, c = threadIdx.x;
  __shared__ float fw[256];
  fw[c] = final_w[o*512 + c];
  __syncthreads();
  float acc = 0.f;
  for (int k = 0; k < 256; ++k) acc += fw[k] * gw_w[k*256 + c];
  M16[o*256 + c] = (bf16_t)acc;
}

// ---------------- xsum[b][c] = sum_hw x[b][c][hw]   grid (16,16) ----------------
__global__ __launch_bounds__(256) void k_xsum(const float* x, float* xsum) {
  int b = blockIdx.y, cx = blockIdx.x;
  int t = threadIdx.x, w = t >> 6, lane = t & 63;
  const float* xb = x + b*262144;
  #pragma unroll
  for (int rr = 0; rr < 4; ++rr) {
    int c = cx*16 + w*4 + rr;
    const f32x4* p = (const f32x4*)(xb + c*1024);
    float s = 0.f;
    #pragma unroll
    for (int k = 0; k < 4; ++k) {
      f32x4 v = p[k*64 + lane];
      s += v[0] + v[1] + v[2] + v[3];
    }
    #pragma unroll
    for (int off = 32; off; off >>= 1) s += __shfl_xor(s, off, 64);
    if (lane == 0) xsum[b*256 + c] = s;
  }
}

// ---------------- fused small graph chain: grid 20, block 256, column-tiled ----------------
__global__ __launch_bounds__(256) void k_graph(const float* emb, const float* adj,
    const float* wq, const float* bq, const float* wk, const float* bk,
    const float* wv, const float* bv, const float* wo, const float* bo,
    const float* gc1_w, const float* gc2_w, const float* final_w,
    int* bar, float* qkv, float* n1, float* n2, float* h1, float* h2,
    float* rg, float* u) {
  int j = blockIdx.x, t = threadIdx.x;
  __shared__ float sA[6144];   // ks | red[16][320] | h2s+g2r | rgs+red2
  __shared__ float sB[6144];   // er/ev [20][304] -> g1s [20][256]
  __shared__ float qrow[304], n2s[304], adjs[400], drt_l[20], att_s[20], p2red[16];
  float* er = sB;
  for (int i = t; i < 6000; i += 256) er[(i/300)*304 + (i%300)] = emb[i];
  if (t < 20) {
    float s = 1.f;
    for (int jj = 0; jj < 20; ++jj) s += adj[t*20 + jj];
    drt_l[t] = rsqrtf(s);
  }
  __syncthreads();
  for (int i = t; i < 400; i += 256) {
    int r = i/20, c2 = i%20;
    float a = adj[i] + (r == c2 ? 1.f : 0.f);
    adjs[i] = drt_l[r] * a * drt_l[c2];
  }
  // ---- P0: qkv col-tiled: 15 blocks x (mat, 60-col chunk) ----
  if (j < 15 && t < 240) {
    int mat = j/5, chunk = j%5;
    const float* Wm = mat==0 ? wq : (mat==1 ? wk : wv);
    const float* Bv = mat==0 ? bq : (mat==1 ? bk : bv);
    int cc = t % 60, rg5 = t / 60;       // rg5 in 0..3; rows rg5+4k
    int c = chunk*60 + cc;
    float a0=0.f,a1=0.f,a2=0.f,a3=0.f,a4=0.f;
    for (int d = 0; d < 300; ++d) {
      float wv_ = Wm[d*300 + c];
      a0 += er[(rg5   )*304 + d] * wv_;
      a1 += er[(rg5+ 4)*304 + d] * wv_;
      a2 += er[(rg5+ 8)*304 + d] * wv_;
      a3 += er[(rg5+12)*304 + d] * wv_;
      a4 += er[(rg5+16)*304 + d] * wv_;
    }
    float bb = Bv[c];
    gst(&qkv[mat*6000 + (rg5   )*300 + c], a0 + bb);
    gst(&qkv[mat*6000 + (rg5+ 4)*300 + c], a1 + bb);
    gst(&qkv[mat*6000 + (rg5+ 8)*300 + c], a2 + bb);
    gst(&qkv[mat*6000 + (rg5+12)*300 + c], a3 + bb);
    gst(&qkv[mat*6000 + (rg5+16)*300 + c], a4 + bb);
  }
  gbar(bar, 0, 20);
  // ---- P1: att row j, n1 partial ----
  {
    float* ks = sA;
    for (int i = t; i < 6000; i += 256) ks[i] = gld(&qkv[6000 + i]);
    for (int i = t; i < 300; i += 256) qrow[i] = gld(&qkv[j*300 + i]);
    __syncthreads();
    if (t < 20) {
      float acc = 0.f;
      #pragma unroll 4
      for (int d = 0; d < 300; ++d) acc += qrow[d] * ks[t*300 + d];
      att_s[t] = acc * 0.05773502691896258f;
    }
    __syncthreads();
    if (t == 0) {
      float m = -1e30f;
      for (int jj = 0; jj < 20; ++jj) m = fmaxf(m, att_s[jj]);
      float s = 0.f;
      for (int jj = 0; jj < 20; ++jj) { float e = __expf(att_s[jj] - m); att_s[jj] = e; s += e; }
      float inv = 0.05f / s;          // includes mean over i (1/20)
      for (int jj = 0; jj < 20; ++jj) att_s[jj] *= inv;
    }
    __syncthreads();
    for (int c = t; c < 300; c += 256) {
      float acc = 0.f;
      for (int jj = 0; jj < 20; ++jj) acc += att_s[jj] * gld(&qkv[12000 + jj*300 + c]);
      atomicAdd(&n1[c], acc);
    }
  }
  gbar(bar, 1, 20);
  // ---- P2: n2 cols [j*15, j*15+15), split-d ----
  for (int i = t; i < 300; i += 256) qrow[i] = gld(&n1[i]);
  if (t < 16) p2red[t] = 0.f;
  __syncthreads();
  if (t < 240) {
    int col = t >> 4, dsub = t & 15;
    int cg = j*15 + col;
    float part = 0.f;
    for (int k = 0; k < 19; ++k) {
      int d = dsub + (k << 4);
      if (d < 300) part += qrow[d] * wo[d*300 + cg];
    }
    atomicAdd(&p2red[col], part);
  }
  __syncthreads();
  if (t < 15) gst(&n2[j*15 + t], p2red[t] + bo[j*15 + t]);
  gbar(bar, 2, 20);
  // ---- P3: ev = emb + n2 (in LDS); h1 col-tiled 16 blocks x 16 cols ----
  for (int i = t; i < 300; i += 256) n2s[i] = gld(&n2[i]);
  __syncthreads();
  for (int i = t; i < 6000; i += 256) er[(i/300)*304 + (i%300)] += n2s[i%300];
  __syncthreads();
  if (j < 16) {
    int col = t & 15, dsub = t >> 4;
    int c = j*16 + col;
    float acc[20];
    #pragma unroll
    for (int r = 0; r < 20; ++r) acc[r] = 0.f;
    for (int k = 0; k < 19; ++k) {
      int d = dsub + (k << 4);
      if (d < 300) {
        float g = gc1_w[d*256 + c];
        #pragma unroll
        for (int r = 0; r < 20; ++r) acc[r] += er[r*304 + d] * g;
      }
    }
    #pragma unroll
    for (int r = 0; r < 20; ++r) sA[dsub*320 + r*16 + col] = acc[r];
  }
  __syncthreads();
  if (j < 16) {
    for (int o = t; o < 320; o += 256) {
      float s = 0.f;
      #pragma unroll
      for (int ds = 0; ds < 16; ++ds) s += sA[ds*320 + o];
      gst(&h1[(o >> 4)*256 + j*16 + (o & 15)], s);
    }
  }
  gbar(bar, 3, 20);
  // ---- P4: g1 full (per block) + h2 col-tiled ----
  if (j < 16) {
    float* g1s = sB;                    // er dead; reuse as g1 [20][256]
    int c = t;
    float h1c[20];
    #pragma unroll
    for (int m = 0; m < 20; ++m) h1c[m] = gld(&h1[m*256 + c]);
    #pragma unroll
    for (int r = 0; r < 20; ++r) {
      float a2 = 0.f;
      #pragma unroll
      for (int m = 0; m < 20; ++m) a2 += adjs[r*20 + m] * h1c[m];
      g1s[r*256 + c] = fmaxf(a2, 0.f);
    }
  }
  __syncthreads();
  if (j < 16) {
    float* g1s = sB;
    int col = t & 15, dsub = t >> 4;
    int cc = j*16 + col;
    float acc[20];
    #pragma unroll
    for (int r = 0; r < 20; ++r) acc[r] = 0.f;
    #pragma unroll 4
    for (int k = 0; k < 16; ++k) {
      int d = dsub + (k << 4);
      float g = gc2_w[d*256 + cc];
      #pragma unroll
      for (int r = 0; r < 20; ++r) acc[r] += g1s[r*256 + d] * g;
    }
    #pragma unroll
    for (int r = 0; r < 20; ++r) sA[dsub*320 + r*16 + col] = acc[r];
  }
  __syncthreads();
  if (j < 16) {
    for (int o = t; o < 320; o += 256) {
      float s = 0.f;
      #pragma unroll
      for (int ds = 0; ds < 16; ++ds) s += sA[ds*320 + o];
      gst(&h2[(o >> 4)*256 + j*16 + (o & 15)], s);
    }
  }
  gbar(bar, 4, 20);
  // ---- P5: g2 + rg, col-owned ----
  if (j < 16) {
    for (int o = t; o < 320; o += 256)
      sA[o] = gld(&h2[(o >> 4)*256 + j*16 + (o & 15)]);   // h2s
  }
  __syncthreads();
  if (j < 16) {
    for (int o = t; o < 320; o += 256) {
      int r = o >> 4, col = o & 15;
      float a = 0.f;
      #pragma unroll
      for (int m = 0; m < 20; ++m) a += adjs[r*20 + m] * sA[m*16 + col];
      sA[320 + o] = fmaxf(a, 0.f);
    }
  }
  __syncthreads();
  if (j < 16 && t < 16) {
    float s = 0.f;
    #pragma unroll
    for (int r = 0; r < 20; ++r) s += sA[320 + r*16 + t];
    gst(&rg[j*16 + t], s);
  }
  gbar(bar, 5, 20);
  // ---- P6: u col-tiled ----
  if (j < 16) sA[t] = gld(&rg[t]);      // rgs[256]
  __syncthreads();
  if (j < 16) {
    int c = j*16 + (t >> 4), ksub = t & 15;
    float s = 0.f;
    #pragma unroll 4
    for (int i = 0; i < 16; ++i) {
      int k = ksub + (i << 4);
      s += final_w[c*512 + 256 + k] * sA[k];
    }
    sA[256 + (t >> 4)*17 + ksub] = s;
  }
  __syncthreads();
  if (j < 16 && t < 16) {
    float s = 0.f;
    #pragma unroll
    for (int k = 0; k < 16; ++k) s += sA[256 + t*17 + k];
    u[j*16 + t] = s;                    // plain store: next-kernel reader (L2 flushed at dispatch end)
  }
}

// ---------------- big path ----------------

// phi -> fBn[b][m][hw] bf16 (phi-flat layout), fmax, csum + cmax, s_raw.
// grid (16, 16): 64 hw per block, 4-way c-split.
__global__ __launch_bounds__(256) void k_phis(const float* x, const float* phi_w,
    const float* phi_b, const float* s2l_w,
    bf16_t* fBn, float* fmaxb, float* s_raw, float* csum, float* cmaxb) {
  int b = blockIdx.y, role = blockIdx.x, t = threadIdx.x;
  const float* xb = x + b*262144;
  __shared__ float pw[4096], wi[256], pb[16];
  __shared__ float phs[4][64][21];
  __shared__ unsigned fmu[16];
  __shared__ unsigned cmu;
  for (int i = t; i < 4096; i += 256) pw[i] = phi_w[i];
  wi[t] = s2l_w[t];
  if (t < 16) { pb[t] = phi_b[t]; fmu[t] = 0u; }
  if (t == 0) cmu = 0u;
  __syncthreads();
  int hwl = t & 63, cq = t >> 6;
  int hw = role*64 + hwl;
  float ph[16];
  #pragma unroll
  for (int o = 0; o < 16; ++o) ph[o] = 0.f;
  float sacc = 0.f;
  for (int ci = 0; ci < 64; ++ci) {
    int c = cq*64 + ci;
    float xv = xb[c*1024 + hw];
    sacc += wi[c] * xv;
    #pragma unroll
    for (int o = 0; o < 16; ++o) ph[o] += pw[o*256 + c] * xv;
  }
  #pragma unroll
  for (int o = 0; o < 16; ++o) phs[cq][hwl][o] = ph[o];
  phs[cq][hwl][16] = sacc;
  __syncthreads();
  for (int idx = t; idx < 64*20; idx += 256) {
    int hh = idx / 20, o = idx % 20;
    if (o < 17)
      phs[0][hh][o] += phs[1][hh][o] + phs[2][hh][o] + phs[3][hh][o];
  }
  __syncthreads();
  if (t < 64) {
    s_raw[b*1024 + hw] = phs[0][hwl][16];
    float cs = 0.f;
    #pragma unroll
    for (int o = 0; o < 16; ++o) {
      float val = fmaxf(phs[0][hwl][o] + pb[o], 0.f);
      bf16_t bv = (bf16_t)val;
      float vf = (float)bv;
      atomicMax(&fmu[o], __float_as_uint(vf));
      cs += vf;
      fBn[b*16384 + o*1024 + hw] = bv;   // natural (phi-flat) layout
    }
    csum[b*1024 + hw] = cs;
    atomicMax(&cmu, __float_as_uint(cs)); // cs >= 0
  }
  __syncthreads();
  if (t < 16) atomicMax((unsigned*)&fmaxb[b*16 + t], fmu[t]);
  if (t == 0) atomicMax((unsigned*)&cmaxb[b], cmu);
}

// dgd = sigmoid(g)-0.5; mcol = softmax_p(s_raw).  grid 16
__global__ __launch_bounds__(256) void k_dgm(const float* xsum, const float* glob_w,
    const float* s_raw, float* dgd, float* mcol) {
  int b = blockIdx.x, t = threadIdx.x;
  __shared__ float xm[256], red[8];
  xm[t] = xsum[b*256 + t] * (1.f / 1024.f);
  __syncthreads();
  if (t < 16) {
    float g = 0.f;
    for (int c = 0; c < 256; ++c) g += glob_w[t*256 + c] * xm[c];
    dgd[b*16 + t] = 0.5f * tanhf(0.5f * g);
  }
  float v[4]; float m = -1e30f;
  #pragma unroll
  for (int i = 0; i < 4; ++i) { v[i] = s_raw[b*1024 + t + i*256]; m = fmaxf(m, v[i]); }
  #pragma unroll
  for (int off = 32; off; off >>= 1) m = fmaxf(m, __shfl_xor(m, off, 64));
  if ((t & 63) == 0) red[t >> 6] = m;
  __syncthreads();
  float bm = fmaxf(fmaxf(red[0], red[1]), fmaxf(red[2], red[3]));
  float e[4]; float sum = 0.f;
  #pragma unroll
  for (int i = 0; i < 4; ++i) { e[i] = __expf(v[i] - bm); sum += e[i]; }
  #pragma unroll
  for (int off = 32; off; off >>= 1) sum += __shfl_xor(sum, off, 64);
  if ((t & 63) == 0) red[4 + (t >> 6)] = sum;
  __syncthreads();
  float inv = 1.f / (red[4] + red[5] + red[6] + red[7]);
  #pragma unroll
  for (int i = 0; i < 4; ++i) mcol[b*1024 + t + i*256] = e[i] * inv;
}

// Fused main (R3 measured-83us structure + XCD swizzle). grid 256, block 256.
__global__ __launch_bounds__(256) void k_main(const float* x, const bf16_t* fBn,
    const bf16_t* M16, const float* fmaxb, const float* mcol, const float* u,
    const float* dgd, const float* csum, const float* cmaxb, float* out) {
  int id = blockIdx.x;
  int b = 2*(id & 7) + (id >> 7);        // same-b blocks -> same XCD
  int p0 = ((id >> 3) & 15) * 64;
  int t = threadIdx.x, w = t >> 6, l = t & 63, lr = l & 15, quad = l >> 4;
  __shared__ __align__(16) char smem[33792];          // union: phase1 | T_ls
  bf16_t* e_s = (bf16_t*)smem;                        // [64][40] e' (m>=16 zero)
  bf16_t* fT  = (bf16_t*)(smem + 5120);               // [32][40] f tile (m>=16 zero)
  bf16_t* PT  = (bf16_t*)(smem + 7680);               // [64][40] E tiles [p][q]
  bf16_t* T_ls = (bf16_t*)smem;                       // [64][264] phase 2
  __shared__ float Mb_s[64], fmax_s[16], u_s[256], rsinv_s[64], dgd_s[16];
  __shared__ float c_s[1024], ha_s[64];
  const float*  xb  = x   + b*262144;
  const bf16_t* fBb = fBn + b*16384;
  for (int i = t; i < 2560; i += 256) e_s[i] = (bf16_t)0.f;
  for (int i = t; i < 1280; i += 256) fT[i] = (bf16_t)0.f;
  u_s[t] = u[t];
  for (int i = t; i < 1024; i += 256) c_s[i] = csum[b*1024 + i];
  if (t < 16) { fmax_s[t] = fmaxb[b*16 + t]; dgd_s[t] = dgd[b*16 + t]; }
  __syncthreads();
  for (int i = t; i < 1024; i += 256) {      // e'[p,m] = x_phi * (sig(g[m])-0.5)
    int p = i >> 4, m = i & 15;
    e_s[p*40 + m] = (bf16_t)((float)fBb[p0*16 + i] * dgd_s[m]);
  }
  __syncthreads();
  if (t < 64) {
    float a = 0.f;
    #pragma unroll
    for (int m = 0; m < 16; ++m) a += (float)fBb[(p0 + t)*16 + m];
    float ha = 0.5f * a;
    ha_s[t] = ha;
    float mb = ha * cmaxb[b];
    #pragma unroll
    for (int m = 0; m < 16; ++m) mb += fmaxf((float)e_s[t*40 + m], 0.f) * fmax_s[m];
    Mb_s[t] = mb;  // exact upper bound on row max of S
  }
  __syncthreads();
  bf16x8 be = *(const bf16x8*)(e_s + (w*16 + lr)*40 + quad*8);  // wave w: p-sub w
  float mb_lane = Mb_s[w*16 + lr];
  float ha_lane = ha_s[w*16 + lr];
  float rs = 0.f;
  f32x4 acc[4][4];  // S2u[p = pf*16+quad*4+r][c = w*64+cf*16+lr]
  #pragma unroll
  for (int i = 0; i < 4; ++i)
    #pragma unroll
    for (int j = 0; j < 4; ++j) acc[i][j] = (f32x4){0.f, 0.f, 0.f, 0.f};
  for (int st = 0; st < 32; ++st) {
    int e0 = t, e1 = t + 256;  // 512 elems: m = e>>5, qi = e&31
    fT[(e0 & 31)*40 + (e0 >> 5)] = fBb[(e0 >> 5)*1024 + st*32 + (e0 & 31)];
    fT[(e1 & 31)*40 + (e1 >> 5)] = fBb[(e1 >> 5)*1024 + st*32 + (e1 & 31)];
    __syncthreads();
    bf16x8 a0 = *(const bf16x8*)(fT + lr*40 + quad*8);
    bf16x8 a1 = *(const bf16x8*)(fT + (16 + lr)*40 + quad*8);
    f32x4 z = {0.f, 0.f, 0.f, 0.f};
    f32x4 s0 = MFMA(a0, be, z);   // D[q=quad*4+r][p=w*16+lr]
    f32x4 s1 = MFMA(a1, be, z);
    bf16x4 p0v, p1v;
    #pragma unroll
    for (int r = 0; r < 4; ++r) {
      float S0 = s0[r] + ha_lane * c_s[st*32 + quad*4 + r];
      float S1 = s1[r] + ha_lane * c_s[st*32 + 16 + quad*4 + r];
      float E0 = __expf(S0 - mb_lane);
      float E1 = __expf(S1 - mb_lane);
      rs += E0 + E1;
      p0v[r] = (bf16_t)E0; p1v[r] = (bf16_t)E1;
    }
    *(bf16x4*)(PT + (w*16 + lr)*40 + quad*4)      = p0v;  // q-local 0..15
    *(bf16x4*)(PT + (w*16 + lr)*40 + 16 + quad*4) = p1v;  // q-local 16..31
    __syncthreads();
    bf16x8 ap[4];
    #pragma unroll
    for (int pf = 0; pf < 4; ++pf)
      ap[pf] = *(const bf16x8*)(PT + (pf*16 + lr)*40 + quad*8);
    #pragma unroll
    for (int cf = 0; cf < 4; ++cf) {
      bf16x8 bv;
      const float* xp = xb + (st*32 + quad*8)*256 + w*64 + cf*16 + lr;
      #pragma unroll
      for (int j = 0; j < 8; ++j) bv[j] = (bf16_t)xp[j*256];   // x_r[q][c] raw reshape
      #pragma unroll
      for (int pf = 0; pf < 4; ++pf) acc[pf][cf] = MFMA(ap[pf], bv, acc[pf][cf]);
    }
  }
  rs += __shfl_xor(rs, 16, 64);
  rs += __shfl_xor(rs, 32, 64);          // full rowsum for p = w*16+lr
  float inv_l = 1.f / fmaxf(rs, 1e-30f);
  if (l < 16) rsinv_s[w*16 + lr] = inv_l;
  __syncthreads();   // rsinv visible; all PT/fT/e_s reads drained -> T_ls may overwrite
  #pragma unroll
  for (int pf = 0; pf < 4; ++pf)
    #pragma unroll
    for (int cf = 0; cf < 4; ++cf)
      #pragma unroll
      for (int r = 0; r < 4; ++r) {
        int p = pf*16 + quad*4 + r;
        int c = w*64 + cf*16 + lr;
        float tv = xb[(p0 + p)*256 + c] - acc[pf][cf][r] * rsinv_s[p];
        T_ls[p*264 + c] = (bf16_t)tv;    // spiral[p][c]
      }
  __syncthreads();
  f32x4 acc2[4][4];  // D2[o = w*64+of*16+quad*4+r][p = pf*16+lr]
  #pragma unroll
  for (int i = 0; i < 4; ++i)
    #pragma unroll
    for (int j = 0; j < 4; ++j) acc2[i][j] = (f32x4){0.f, 0.f, 0.f, 0.f};
  for (int c0 = 0; c0 < 256; c0 += 32) {
    bf16x8 am[4], bt[4];
    #pragma unroll
    for (int of = 0; of < 4; ++of)
      am[of] = *(const bf16x8*)(M16 + (w*64 + of*16 + lr)*256 + c0 + quad*8);
    #pragma unroll
    for (int pf = 0; pf < 4; ++pf)
      bt[pf] = *(const bf16x8*)(T_ls + (pf*16 + lr)*264 + c0 + quad*8);
    #pragma unroll
    for (int of = 0; of < 4; ++of)
      #pragma unroll
      for (int pf = 0; pf < 4; ++pf) acc2[of][pf] = MFMA(am[of], bt[pf], acc2[of][pf]);
  }
  float* outb = out + b*262144;
  #pragma unroll
  for (int of = 0; of < 4; ++of)
    #pragma unroll
    for (int pf = 0; pf < 4; ++pf)
      #pragma unroll
      for (int r = 0; r < 4; ++r) {
        int o = w*64 + of*16 + quad*4 + r;
        int pg = p0 + pf*16 + lr;
        float v = acc2[of][pf][r] + mcol[b*1024 + pg] * u_s[o] + xb[o*1024 + pg];
        outb[o*1024 + pg] = fmaxf(v, 0.f);
      }
}

// ---------------- launch ----------------

extern "C" void kernel_launch(void* const* d_in, const int* in_sizes, int n_in,
                              void* d_out, int out_size, void* d_ws, size_t ws_size,
                              hipStream_t stream) {
  (void)in_sizes; (void)n_in; (void)out_size; (void)ws_size;
  const float* x       = (const float*)d_in[0];
  const float* emb     = (const float*)d_in[1];
  const float* adj     = (const float*)d_in[2];
  const float* wq      = (const float*)d_in[3];
  const float* bq      = (const float*)d_in[4];
  const float* wk      = (const float*)d_in[5];
  const float* bk      = (const float*)d_in[6];
  const float* wv      = (const float*)d_in[7];
  const float* bv      = (const float*)d_in[8];
  const float* wo      = (const float*)d_in[9];
  const float* bo      = (const float*)d_in[10];
  const float* phi_w   = (const float*)d_in[11];
  const float* phi_b   = (const float*)d_in[12];
  const float* glob_w  = (const float*)d_in[13];
  const float* gc1_w   = (const float*)d_in[14];
  const float* gc2_w   = (const float*)d_in[15];
  const float* gw_w    = (const float*)d_in[16];
  const float* s2l_w   = (const float*)d_in[17];
  const float* final_w = (const float*)d_in[19];
  float* out = (float*)d_out;

  float* W = (float*)d_ws;
  // zero region [0, 4960 floats): bar | rg | n1 | xsum | fmaxb | cmaxb
  int*   bar   = (int*)W;          // 32 ints
  float* rg    = W + 32;           // 256
  float* n1    = W + 288;          // 304
  float* xsum  = W + 592;          // 4096
  float* fmaxb = W + 4688;         // 256
  float* cmaxb = W + 4944;         // 16
  float* qkv   = W + 4960;         // 18000
  float* n2    = W + 22960;        // 304
  float* h1    = W + 23264;        // 5120
  float* h2    = W + 28384;        // 5120
  float* u     = W + 33504;        // 256
  float* s_raw = W + 33760;        // 16384
  float* mcol  = W + 50144;        // 16384
  float* csum  = W + 66528;        // 16384
  float* dgd   = W + 82912;        // 256
  bf16_t* M16 = (bf16_t*)((char*)d_ws + 335872);   // 128 KB
  bf16_t* fBn = (bf16_t*)((char*)d_ws + 466944);   // 512 KB (16 x 16 x 1024, phi-flat)
  // total ws usage ~1.0 MB

  hipMemsetAsync(d_ws, 0, 4960 * sizeof(float), stream);
  k_graph<<<20, 256, 0, stream>>>(emb, adj, wq, bq, wk, bk, wv, bv, wo, bo,
                                  gc1_w, gc2_w, final_w, bar, qkv, n1, n2, h1, h2, rg, u);
  k_phis <<<dim3(16, 16), 256, 0, stream>>>(x, phi_w, phi_b, s2l_w, fBn, fmaxb, s_raw, csum, cmaxb);
  k_xsum <<<dim3(16, 16), 256, 0, stream>>>(x, xsum);
  k_M    <<<256, 256, 0, stream>>>(final_w, gw_w, M16);
  k_dgm  <<<16, 256, 0, stream>>>(xsum, glob_w, s_raw, dgd, mcol);
  k_main <<<256, 256, 0, stream>>>(x, fBn, M16, fmaxb, mcol, u, dgd, csum, cmaxb, out);
}